// Round 8
// baseline (499.418 us; speedup 1.0000x reference)
//
#include <hip/hip_runtime.h>
#include <hip/hip_fp16.h>

// LightGCN 3-layer propagation, pull-based CSR, fp16 ego intermediates.
// Round 14: gather is at its structural floor (unroll-2 was a null: BW
// pinned at 3.85 TB/s ~= per-CU outstanding-miss limit on random 128B
// rows; every miss is a fully-used row). Attack prep (108us) instead:
// replace the bucket chain (hist/scan/scatter/csr_finalize) with a direct
// node-level CSR build:
//   edge_hist:  2M fire-and-forget global atomics into nodeCount (600KB,
//               L2-resident)
//   scanA/B/C:  3-stage exclusive scan of 150K counts -> rowPtr, cur
//   edge_scatter: pos = atomicAdd(&cur[src]); pairs[pos] = [norm|dst]
// This deletes csr_finalize (16MB R + 16MB W + LDS sort) and the bpair
// buffer outright. Gather kept byte-identical to the verified round-13
// kernel (75.4us/launch); pairs packing loses the now-unneeded src_local
// bits (gather already masks lo & 0x3FFFF).

#define NUM_USERS 100000
#define NUM_ITEMS 50000
#define EMB_DIM   64
#define N_EDGES   2000000
#define N_NODES   (NUM_USERS + NUM_ITEMS)          // 150000
#define NODE_FLOATS (N_NODES * EMB_DIM)            // 9,600,000
#define NODE_F4     (NODE_FLOATS / 4)              // 2,400,000

#define NE4      (N_EDGES / 4)                     // 500000 int4 groups
#define EHB      ((NE4 + 255) / 256)               // 1954 blocks, 4 edges/thr

#define CHUNK    1024
#define NCHUNK   ((N_NODES + CHUNK - 1) / CHUNK)   // 147

typedef unsigned int uint;
typedef unsigned short ushort;
typedef unsigned long long u64;

__device__ __forceinline__ float2 h2f2(uint u) {
    __half2 h = *reinterpret_cast<const __half2*>(&u);
    return __half22float2(h);
}
__device__ __forceinline__ uint f2h2(float a, float b) {
    __half2 h = __floats2half2_rn(a, b);
    return *reinterpret_cast<uint*>(&h);
}

// ---------- init: egoA(fp16) = concat(user,item); zero nodeCount ----------
__global__ void lgcn_init(const float4* __restrict__ user,
                          const float4* __restrict__ item,
                          uint2* __restrict__ egoA,
                          int* __restrict__ nodeCount) {
    const int n_user4 = NUM_USERS * EMB_DIM / 4;
    int stride = gridDim.x * blockDim.x;
    int gid = blockIdx.x * blockDim.x + threadIdx.x;
    for (int i = gid; i < N_NODES; i += stride) nodeCount[i] = 0;
    for (int i = gid; i < NODE_F4; i += stride) {
        float4 v = (i < n_user4) ? user[i] : item[i - n_user4];
        egoA[i] = make_uint2(f2h2(v.x, v.y), f2h2(v.z, v.w));
    }
}

// ---------- per-node histogram: fire-and-forget global atomics ----------
__global__ __launch_bounds__(256) void edge_hist(const int4* __restrict__ src4,
                                                 int* __restrict__ nodeCount) {
    int i = blockIdx.x * blockDim.x + threadIdx.x;
    if (i >= NE4) return;
    int4 s = src4[i];
    atomicAdd(&nodeCount[s.x], 1);
    atomicAdd(&nodeCount[s.y], 1);
    atomicAdd(&nodeCount[s.z], 1);
    atomicAdd(&nodeCount[s.w], 1);
}

// ---------- scanA: per-chunk sums ----------
__global__ __launch_bounds__(CHUNK) void scanA(const int* __restrict__ nodeCount,
                                               int* __restrict__ chunkSum) {
    __shared__ int s[CHUNK];
    int t = threadIdx.x;
    int node = blockIdx.x * CHUNK + t;
    s[t] = (node < N_NODES) ? nodeCount[node] : 0;
    __syncthreads();
    for (int off = CHUNK / 2; off > 0; off >>= 1) {
        if (t < off) s[t] += s[t + off];
        __syncthreads();
    }
    if (t == 0) chunkSum[blockIdx.x] = s[0];
}

// ---------- scanB: exclusive scan of 147 chunk sums (1 block) ----------
__global__ __launch_bounds__(256) void scanB(const int* __restrict__ chunkSum,
                                             int* __restrict__ chunkOff,
                                             int* __restrict__ rowPtr) {
    __shared__ int s[256];
    int t = threadIdx.x;
    int v = (t < NCHUNK) ? chunkSum[t] : 0;
    s[t] = v;
    __syncthreads();
    for (int off = 1; off < 256; off <<= 1) {
        int x = (t >= off) ? s[t - off] : 0;
        __syncthreads();
        s[t] += x;
        __syncthreads();
    }
    if (t < NCHUNK) chunkOff[t] = s[t] - v;       // exclusive
    if (t == 0) rowPtr[N_NODES] = N_EDGES;
}

// ---------- scanC: per-chunk exclusive scan + offset -> rowPtr, cur ----------
__global__ __launch_bounds__(CHUNK) void scanC(const int* __restrict__ nodeCount,
                                               const int* __restrict__ chunkOff,
                                               int* __restrict__ rowPtr,
                                               int* __restrict__ cur) {
    __shared__ int s[CHUNK];
    int t = threadIdx.x;
    int node = blockIdx.x * CHUNK + t;
    int v = (node < N_NODES) ? nodeCount[node] : 0;
    s[t] = v;
    __syncthreads();
    for (int off = 1; off < CHUNK; off <<= 1) {
        int x = (t >= off) ? s[t - off] : 0;
        __syncthreads();
        s[t] += x;
        __syncthreads();
    }
    if (node < N_NODES) {
        int val = chunkOff[blockIdx.x] + s[t] - v;  // exclusive
        rowPtr[node] = val;
        cur[node] = val;
    }
}

// ---------- scatter: pos = atomicAdd(cur[src]); pairs[pos] = [norm|dst] ----
__global__ __launch_bounds__(256) void edge_scatter(const int4* __restrict__ src4,
                                                    const int4* __restrict__ dst4,
                                                    const float4* __restrict__ norm4,
                                                    int* __restrict__ cur,
                                                    u64* __restrict__ pairs) {
    int i = blockIdx.x * blockDim.x + threadIdx.x;
    if (i >= NE4) return;
    int4 s = src4[i];
    int4 d = dst4[i];
    float4 n = norm4[i];
    int p0 = atomicAdd(&cur[s.x], 1);
    pairs[p0] = (u64)(uint)d.x | ((u64)(uint)__float_as_uint(n.x) << 32);
    int p1 = atomicAdd(&cur[s.y], 1);
    pairs[p1] = (u64)(uint)d.y | ((u64)(uint)__float_as_uint(n.y) << 32);
    int p2 = atomicAdd(&cur[s.z], 1);
    pairs[p2] = (u64)(uint)d.z | ((u64)(uint)__float_as_uint(n.z) << 32);
    int p3 = atomicAdd(&cur[s.w], 1);
    pairs[p3] = (u64)(uint)d.w | ((u64)(uint)__float_as_uint(n.w) << 32);
}

// ---------- gather: 2 nodes/wave, 4 streams x 2-deep unroll per node ----------
// (verified round-13 kernel, unchanged)
// finalMode==0: nego = fp16(s)                    (no acc access)
// finalMode==1: acc  = (e0 + e1 + ego + s) * 0.25 (no nego write)
__global__ void lgcn_gather(const ushort* __restrict__ ego,
                            ushort* __restrict__ nego,
                            float* __restrict__ acc,
                            const ushort* __restrict__ e0,
                            const ushort* __restrict__ e1,
                            const int* __restrict__ rowPtr,
                            const u64* __restrict__ pairs,
                            int finalMode) {
    // 256 threads = 4 waves = 8 nodes (one node per 32-lane half-wave)
    int node   = blockIdx.x * 8 + (threadIdx.x >> 5);
    int lane32 = threadIdx.x & 31;
    int g      = lane32 >> 3;       // 4 edge streams per node
    int sub    = lane32 & 7;        // uint4 position within the 128B row
    if (node >= N_NODES) return;
    int beg = rowPtr[node];
    int end = rowPtr[node + 1];

    float a0 = 0.f, a1 = 0.f, a2 = 0.f, a3 = 0.f;
    float a4 = 0.f, a5 = 0.f, a6 = 0.f, a7 = 0.f;
    float b0 = 0.f, b1 = 0.f, b2 = 0.f, b3 = 0.f;
    float b4 = 0.f, b5 = 0.f, b6 = 0.f, b7 = 0.f;

    int i = beg + g;
    for (; i + 4 < end; i += 8) {
        u64 pA = pairs[i];
        u64 pB = pairs[i + 4];
        uint loA = (uint)pA, loB = (uint)pB;
        float wA = __uint_as_float((uint)(pA >> 32));
        float wB = __uint_as_float((uint)(pB >> 32));
        uint4 rA = *(const uint4*)(ego + ((size_t)(loA & 0x3FFFF) << 6) + (sub << 3));
        uint4 rB = *(const uint4*)(ego + ((size_t)(loB & 0x3FFFF) << 6) + (sub << 3));
        float2 q;
        q = h2f2(rA.x); a0 += wA * q.x; a1 += wA * q.y;
        q = h2f2(rA.y); a2 += wA * q.x; a3 += wA * q.y;
        q = h2f2(rA.z); a4 += wA * q.x; a5 += wA * q.y;
        q = h2f2(rA.w); a6 += wA * q.x; a7 += wA * q.y;
        q = h2f2(rB.x); b0 += wB * q.x; b1 += wB * q.y;
        q = h2f2(rB.y); b2 += wB * q.x; b3 += wB * q.y;
        q = h2f2(rB.z); b4 += wB * q.x; b5 += wB * q.y;
        q = h2f2(rB.w); b6 += wB * q.x; b7 += wB * q.y;
    }
    if (i < end) {
        u64 p = pairs[i];
        uint lo = (uint)p;
        float w = __uint_as_float((uint)(p >> 32));
        uint4 r = *(const uint4*)(ego + ((size_t)(lo & 0x3FFFF) << 6) + (sub << 3));
        float2 q;
        q = h2f2(r.x); a0 += w * q.x; a1 += w * q.y;
        q = h2f2(r.y); a2 += w * q.x; a3 += w * q.y;
        q = h2f2(r.z); a4 += w * q.x; a5 += w * q.y;
        q = h2f2(r.w); a6 += w * q.x; a7 += w * q.y;
    }
    float s0 = a0 + b0, s1 = a1 + b1, s2 = a2 + b2, s3 = a3 + b3;
    float s4 = a4 + b4, s5 = a5 + b5, s6 = a6 + b6, s7 = a7 + b7;

    s0 += __shfl_down(s0, 16); s1 += __shfl_down(s1, 16);
    s2 += __shfl_down(s2, 16); s3 += __shfl_down(s3, 16);
    s4 += __shfl_down(s4, 16); s5 += __shfl_down(s5, 16);
    s6 += __shfl_down(s6, 16); s7 += __shfl_down(s7, 16);
    s0 += __shfl_down(s0, 8);  s1 += __shfl_down(s1, 8);
    s2 += __shfl_down(s2, 8);  s3 += __shfl_down(s3, 8);
    s4 += __shfl_down(s4, 8);  s5 += __shfl_down(s5, 8);
    s6 += __shfl_down(s6, 8);  s7 += __shfl_down(s7, 8);

    if (lane32 < 8) {
        size_t ro = ((size_t)node << 6) + (lane32 << 3);   // dims lane32*8..+7
        if (!finalMode) {
            uint4* np = (uint4*)(nego + ro);
            *np = make_uint4(f2h2(s0, s1), f2h2(s2, s3),
                             f2h2(s4, s5), f2h2(s6, s7));
        } else {
            uint4 z0 = *(const uint4*)(e0  + ro);
            uint4 z1 = *(const uint4*)(e1  + ro);
            uint4 z2 = *(const uint4*)(ego + ro);
            float2 a, b, c;
            float4 o0, o1;
            a = h2f2(z0.x); b = h2f2(z1.x); c = h2f2(z2.x);
            o0.x = (a.x + b.x + c.x + s0) * 0.25f;
            o0.y = (a.y + b.y + c.y + s1) * 0.25f;
            a = h2f2(z0.y); b = h2f2(z1.y); c = h2f2(z2.y);
            o0.z = (a.x + b.x + c.x + s2) * 0.25f;
            o0.w = (a.y + b.y + c.y + s3) * 0.25f;
            a = h2f2(z0.z); b = h2f2(z1.z); c = h2f2(z2.z);
            o1.x = (a.x + b.x + c.x + s4) * 0.25f;
            o1.y = (a.y + b.y + c.y + s5) * 0.25f;
            a = h2f2(z0.w); b = h2f2(z1.w); c = h2f2(z2.w);
            o1.z = (a.x + b.x + c.x + s6) * 0.25f;
            o1.w = (a.y + b.y + c.y + s7) * 0.25f;
            float4* ap = (float4*)(acc + ro);
            ap[0] = o0;
            ap[1] = o1;
        }
    }
}

extern "C" void kernel_launch(void* const* d_in, const int* in_sizes, int n_in,
                              void* d_out, int out_size, void* d_ws, size_t ws_size,
                              hipStream_t stream) {
    const float* user_emb  = (const float*)d_in[0];
    const float* item_emb  = (const float*)d_in[1];
    const float* edge_norm = (const float*)d_in[2];
    const int*   edge_src  = (const int*)d_in[3];
    const int*   edge_dst  = (const int*)d_in[4];
    float* acc = (float*)d_out;

    char* w = (char*)d_ws;
    ushort* egoA  = (ushort*)w;                      w += (size_t)NODE_FLOATS * 2;   // 19.2 MB
    ushort* egoB  = (ushort*)w;                      w += (size_t)NODE_FLOATS * 2;   // 19.2 MB
    u64*   pairs  = (u64*)w;                         w += (size_t)N_EDGES * 8;       // 16 MB
    int*   rowPtr = (int*)w;                         w += (size_t)(N_NODES + 4) * 4; // 0.6 MB
    // egoC (born at layer-2 gather) overlays the prep scratch (nodeCount,
    // cur, chunk arrays) — all dead after edge_scatter.
    ushort* egoC      = (ushort*)w;                                                  // 19.2 MB
    int*   nodeCount  = (int*)w;                     w += (size_t)N_NODES * 4;       // 0.6 MB
    int*   cur        = (int*)w;                     w += (size_t)N_NODES * 4;       // 0.6 MB
    int*   chunkSum   = (int*)w;                     w += (size_t)(NCHUNK + 1) * 4;
    int*   chunkOff   = (int*)w;

    const int T = 256;
    const int EW_BLOCKS = 2048;
    const int GATHER_BLOCKS = (N_NODES + 7) / 8;     // 18750

    lgcn_init<<<EW_BLOCKS, T, 0, stream>>>(
        (const float4*)user_emb, (const float4*)item_emb, (uint2*)egoA,
        nodeCount);

    edge_hist<<<EHB, T, 0, stream>>>((const int4*)edge_src, nodeCount);
    scanA<<<NCHUNK, CHUNK, 0, stream>>>(nodeCount, chunkSum);
    scanB<<<1, 256, 0, stream>>>(chunkSum, chunkOff, rowPtr);
    scanC<<<NCHUNK, CHUNK, 0, stream>>>(nodeCount, chunkOff, rowPtr, cur);
    edge_scatter<<<EHB, T, 0, stream>>>((const int4*)edge_src,
                                        (const int4*)edge_dst,
                                        (const float4*)edge_norm,
                                        cur, pairs);

    // Layer 1: ego0(A) -> ego1(B)             (nego only)
    lgcn_gather<<<GATHER_BLOCKS, T, 0, stream>>>(egoA, egoB, acc,
                                                 (const ushort*)0, (const ushort*)0,
                                                 rowPtr, pairs, 0);
    // Layer 2: ego1(B) -> ego2(C)             (nego only)
    lgcn_gather<<<GATHER_BLOCKS, T, 0, stream>>>(egoB, egoC, acc,
                                                 (const ushort*)0, (const ushort*)0,
                                                 rowPtr, pairs, 0);
    // Layer 3: ego2(C) -> s; acc = (A + B + C + s) / 4
    lgcn_gather<<<GATHER_BLOCKS, T, 0, stream>>>(egoC, (ushort*)0, acc,
                                                 egoA, egoB,
                                                 rowPtr, pairs, 1);
}

// Round 9
// 331.237 us; speedup vs baseline: 1.5077x; 1.5077x over previous
//
#include <hip/hip_runtime.h>
#include <hip/hip_fp16.h>

// LightGCN 3-layer propagation, pull-based CSR, fp16 ego intermediates.
// Round 15: REVERT round-14's direct CSR build (edge_scatter's random 8B
// writes hit 8x sector amplification: WRITE_SIZE 125MB for a 16MB array,
// 175us alone — the bucket chain's reserved contiguous runs exist exactly
// to keep scatter writes sector-dense). Base = verified round-13 (334.4us).
// ONE change: csr_finalize's counting-sort key widens from src_local to
// (src_local, dst>>15) — 293x5=1465 bins — so each node's edge list comes
// out dst-range-sorted. All concurrent gather waves then walk the same
// dst window (~32K nodes x 128B = 4.2MB ~ one XCD L2) at the same time,
// manufacturing temporal locality on the random row reads. Scatter and
// gather byte-identical; only within-node edge order changes.

#define NUM_USERS 100000
#define NUM_ITEMS 50000
#define EMB_DIM   64
#define N_EDGES   2000000
#define N_NODES   (NUM_USERS + NUM_ITEMS)          // 150000
#define NODE_FLOATS (N_NODES * EMB_DIM)            // 9,600,000
#define NODE_F4     (NODE_FLOATS / 4)              // 2,400,000

#define NBUCKET  512
#define NPB      293        // nodes per bucket; 512*293 = 150016 >= 150000
#define NPART    8          // reservation partitions (XCD heuristic)
#define NCNT     (NBUCKET * NPART)                  // 4096
#define BT       512        // threads in bucket passes
#define VPT      8          // edges per thread in bucket passes
#define TILE     (BT * VPT)                         // 4096
#define NTILE    ((N_EDGES + TILE - 1) / TILE)      // 489

#define NQ       5          // dst quadrants: dst>>15 in 0..4
#define NBIN     (NPB * NQ) // 1465 sort bins per bucket
#define NBIN2    2048       // padded scan width (pair-trick, 1024 threads)

typedef unsigned int uint;
typedef unsigned short ushort;
typedef unsigned long long u64;

__device__ __forceinline__ float2 h2f2(uint u) {
    __half2 h = *reinterpret_cast<const __half2*>(&u);
    return __half22float2(h);
}
__device__ __forceinline__ uint f2h2(float a, float b) {
    __half2 h = __floats2half2_rn(a, b);
    return *reinterpret_cast<uint*>(&h);
}

// ---------- init: egoA(fp16) = concat(user,item) ----------
__global__ void lgcn_init(const float4* __restrict__ user,
                          const float4* __restrict__ item,
                          uint2* __restrict__ egoA) {
    const int n_user4 = NUM_USERS * EMB_DIM / 4;
    for (int i = blockIdx.x * blockDim.x + threadIdx.x; i < NODE_F4;
         i += gridDim.x * blockDim.x) {
        float4 v = (i < n_user4) ? user[i] : item[i - n_user4];
        egoA[i] = make_uint2(f2h2(v.x, v.y), f2h2(v.z, v.w));
    }
}

__global__ void zero_ints(int* __restrict__ p, int n) {
    int i = blockIdx.x * blockDim.x + threadIdx.x;
    if (i < n) p[i] = 0;
}

// ---------- pass A: histogram into (bucket, partition) counters ----------
__global__ __launch_bounds__(BT) void bucket_hist(const int* __restrict__ src,
                                                  int* __restrict__ bucketCount) {
    __shared__ int cnt[NBUCKET];
    int t = threadIdx.x;
    int part = blockIdx.x & (NPART - 1);
    cnt[t] = 0;
    __syncthreads();
    int base = blockIdx.x * TILE + t;
    #pragma unroll
    for (int k = 0; k < VPT; ++k) {
        int e = base + k * BT;
        if (e < N_EDGES) atomicAdd(&cnt[src[e] / NPB], 1);
    }
    __syncthreads();
    int c = cnt[t];
    if (c) atomicAdd(&bucketCount[t * NPART + part], c);
}

// ---------- scan over 4096 (bucket,part) counters (1 block, 1024 thr) ----------
__global__ __launch_bounds__(1024) void bucket_scan(const int* __restrict__ bucketCount,
                                                    int* __restrict__ bucketOffset,
                                                    int* __restrict__ gCur,
                                                    int* __restrict__ rowPtr) {
    __shared__ int s[1024];
    int t = threadIdx.x;
    int4 c = *(const int4*)(bucketCount + t * 4);
    int sum = c.x + c.y + c.z + c.w;
    s[t] = sum;
    __syncthreads();
    for (int off = 1; off < 1024; off <<= 1) {
        int x = (t >= off) ? s[t - off] : 0;
        __syncthreads();
        s[t] += x;
        __syncthreads();
    }
    int base = s[t] - sum;   // exclusive
    int i0 = t * 4;
    bucketOffset[i0]     = base;
    bucketOffset[i0 + 1] = base + c.x;
    bucketOffset[i0 + 2] = base + c.x + c.y;
    bucketOffset[i0 + 3] = base + c.x + c.y + c.z;
    gCur[i0]     = base;
    gCur[i0 + 1] = base + c.x;
    gCur[i0 + 2] = base + c.x + c.y;
    gCur[i0 + 3] = base + c.x + c.y + c.z;
    if (t == 0) {
        bucketOffset[NCNT] = N_EDGES;
        rowPtr[N_NODES] = N_EDGES;
    }
}

// ---------- pass B: scatter packed edges into (bucket,part) runs ----------
// packed u64: [norm:32][src_local:9][dst:18]
__global__ __launch_bounds__(BT) void bucket_scatter(const int* __restrict__ src,
                                                     const int* __restrict__ dst,
                                                     const float* __restrict__ norm,
                                                     int* __restrict__ gCur,
                                                     u64* __restrict__ bpair) {
    __shared__ int cnt[NBUCKET];
    __shared__ int bbase[NBUCKET];
    int t = threadIdx.x;
    int part = blockIdx.x & (NPART - 1);
    cnt[t] = 0;
    __syncthreads();
    int base = blockIdx.x * TILE + t;
    #pragma unroll
    for (int k = 0; k < VPT; ++k) {
        int e = base + k * BT;
        if (e < N_EDGES) atomicAdd(&cnt[src[e] / NPB], 1);
    }
    __syncthreads();
    int c = cnt[t];
    bbase[t] = c ? atomicAdd(&gCur[t * NPART + part], c) : 0;
    __syncthreads();
    cnt[t] = 0;
    __syncthreads();
    #pragma unroll
    for (int k = 0; k < VPT; ++k) {
        int e = base + k * BT;
        if (e < N_EDGES) {
            int s = src[e];
            int b = s / NPB;
            int sl = s - b * NPB;                    // 0..292
            int r = atomicAdd(&cnt[b], 1);
            uint lo = (uint)dst[e] | ((uint)sl << 18);
            u64 packed = (u64)lo | ((u64)(uint)__float_as_uint(norm[e]) << 32);
            bpair[bbase[b] + r] = packed;
        }
    }
}

// ---------- pass C: per-bucket counting sort by (src_local, dst>>15) ----------
// Wider key than round-13 (was src_local only): each node's run comes out
// dst-range-sorted, manufacturing a synchronized dst sweep in the gather.
__global__ __launch_bounds__(1024) void csr_finalize(const int* __restrict__ bucketOffset,
                                                     const u64* __restrict__ bpair,
                                                     int* __restrict__ rowPtr,
                                                     u64* __restrict__ pairs) {
    __shared__ int cnt[NBIN2];      // 8 KB
    __shared__ int cur[NBIN2];      // 8 KB
    __shared__ int psum[1024];      // 4 KB
    int b = blockIdx.x;
    int t = threadIdx.x;            // 1024 threads
    int beg = bucketOffset[b * NPART];
    int end = bucketOffset[b * NPART + NPART];
    int nodeBase = b * NPB;

    cnt[t] = 0;
    cnt[t + 1024] = 0;
    __syncthreads();
    for (int i = beg + t; i < end; i += 1024) {
        uint lo = (uint)bpair[i];
        int sl = (lo >> 18) & 0x1FF;
        int q  = (lo & 0x3FFFF) >> 15;               // 0..4
        atomicAdd(&cnt[sl * NQ + q], 1);
    }
    __syncthreads();
    // exclusive scan over 2048 bins: thread t owns bins 2t, 2t+1
    int c0 = cnt[2 * t];
    int c1 = cnt[2 * t + 1];
    int ps = c0 + c1;
    psum[t] = ps;
    __syncthreads();
    for (int off = 1; off < 1024; off <<= 1) {
        int x = (t >= off) ? psum[t - off] : 0;
        __syncthreads();
        psum[t] += x;
        __syncthreads();
    }
    int base = psum[t] - ps;        // exclusive over bin pairs
    cur[2 * t]     = base;
    cur[2 * t + 1] = base + c0;
    __syncthreads();
    if (t < NPB) {
        int node = nodeBase + t;
        if (node < N_NODES) rowPtr[node] = beg + cur[t * NQ];
    }
    __syncthreads();
    for (int i = beg + t; i < end; i += 1024) {
        u64 p = bpair[i];
        uint lo = (uint)p;
        int sl = (lo >> 18) & 0x1FF;
        int q  = (lo & 0x3FFFF) >> 15;
        int r = atomicAdd(&cur[sl * NQ + q], 1);
        pairs[beg + r] = p;
    }
}

// ---------- gather: 2 nodes/wave, 4 streams x 2-deep unroll per node ----------
// (verified round-13 kernel, unchanged)
// finalMode==0: nego = fp16(s)                    (no acc access)
// finalMode==1: acc  = (e0 + e1 + ego + s) * 0.25 (no nego write)
__global__ void lgcn_gather(const ushort* __restrict__ ego,
                            ushort* __restrict__ nego,
                            float* __restrict__ acc,
                            const ushort* __restrict__ e0,
                            const ushort* __restrict__ e1,
                            const int* __restrict__ rowPtr,
                            const u64* __restrict__ pairs,
                            int finalMode) {
    // 256 threads = 4 waves = 8 nodes (one node per 32-lane half-wave)
    int node   = blockIdx.x * 8 + (threadIdx.x >> 5);
    int lane32 = threadIdx.x & 31;
    int g      = lane32 >> 3;       // 4 edge streams per node
    int sub    = lane32 & 7;        // uint4 position within the 128B row
    if (node >= N_NODES) return;
    int beg = rowPtr[node];
    int end = rowPtr[node + 1];

    float a0 = 0.f, a1 = 0.f, a2 = 0.f, a3 = 0.f;
    float a4 = 0.f, a5 = 0.f, a6 = 0.f, a7 = 0.f;
    float b0 = 0.f, b1 = 0.f, b2 = 0.f, b3 = 0.f;
    float b4 = 0.f, b5 = 0.f, b6 = 0.f, b7 = 0.f;

    int i = beg + g;
    for (; i + 4 < end; i += 8) {
        u64 pA = pairs[i];
        u64 pB = pairs[i + 4];
        uint loA = (uint)pA, loB = (uint)pB;
        float wA = __uint_as_float((uint)(pA >> 32));
        float wB = __uint_as_float((uint)(pB >> 32));
        uint4 rA = *(const uint4*)(ego + ((size_t)(loA & 0x3FFFF) << 6) + (sub << 3));
        uint4 rB = *(const uint4*)(ego + ((size_t)(loB & 0x3FFFF) << 6) + (sub << 3));
        float2 q;
        q = h2f2(rA.x); a0 += wA * q.x; a1 += wA * q.y;
        q = h2f2(rA.y); a2 += wA * q.x; a3 += wA * q.y;
        q = h2f2(rA.z); a4 += wA * q.x; a5 += wA * q.y;
        q = h2f2(rA.w); a6 += wA * q.x; a7 += wA * q.y;
        q = h2f2(rB.x); b0 += wB * q.x; b1 += wB * q.y;
        q = h2f2(rB.y); b2 += wB * q.x; b3 += wB * q.y;
        q = h2f2(rB.z); b4 += wB * q.x; b5 += wB * q.y;
        q = h2f2(rB.w); b6 += wB * q.x; b7 += wB * q.y;
    }
    if (i < end) {
        u64 p = pairs[i];
        uint lo = (uint)p;
        float w = __uint_as_float((uint)(p >> 32));
        uint4 r = *(const uint4*)(ego + ((size_t)(lo & 0x3FFFF) << 6) + (sub << 3));
        float2 q;
        q = h2f2(r.x); a0 += w * q.x; a1 += w * q.y;
        q = h2f2(r.y); a2 += w * q.x; a3 += w * q.y;
        q = h2f2(r.z); a4 += w * q.x; a5 += w * q.y;
        q = h2f2(r.w); a6 += w * q.x; a7 += w * q.y;
    }
    float s0 = a0 + b0, s1 = a1 + b1, s2 = a2 + b2, s3 = a3 + b3;
    float s4 = a4 + b4, s5 = a5 + b5, s6 = a6 + b6, s7 = a7 + b7;

    s0 += __shfl_down(s0, 16); s1 += __shfl_down(s1, 16);
    s2 += __shfl_down(s2, 16); s3 += __shfl_down(s3, 16);
    s4 += __shfl_down(s4, 16); s5 += __shfl_down(s5, 16);
    s6 += __shfl_down(s6, 16); s7 += __shfl_down(s7, 16);
    s0 += __shfl_down(s0, 8);  s1 += __shfl_down(s1, 8);
    s2 += __shfl_down(s2, 8);  s3 += __shfl_down(s3, 8);
    s4 += __shfl_down(s4, 8);  s5 += __shfl_down(s5, 8);
    s6 += __shfl_down(s6, 8);  s7 += __shfl_down(s7, 8);

    if (lane32 < 8) {
        size_t ro = ((size_t)node << 6) + (lane32 << 3);   // dims lane32*8..+7
        if (!finalMode) {
            uint4* np = (uint4*)(nego + ro);
            *np = make_uint4(f2h2(s0, s1), f2h2(s2, s3),
                             f2h2(s4, s5), f2h2(s6, s7));
        } else {
            uint4 z0 = *(const uint4*)(e0  + ro);
            uint4 z1 = *(const uint4*)(e1  + ro);
            uint4 z2 = *(const uint4*)(ego + ro);
            float2 a, b, c;
            float4 o0, o1;
            a = h2f2(z0.x); b = h2f2(z1.x); c = h2f2(z2.x);
            o0.x = (a.x + b.x + c.x + s0) * 0.25f;
            o0.y = (a.y + b.y + c.y + s1) * 0.25f;
            a = h2f2(z0.y); b = h2f2(z1.y); c = h2f2(z2.y);
            o0.z = (a.x + b.x + c.x + s2) * 0.25f;
            o0.w = (a.y + b.y + c.y + s3) * 0.25f;
            a = h2f2(z0.z); b = h2f2(z1.z); c = h2f2(z2.z);
            o1.x = (a.x + b.x + c.x + s4) * 0.25f;
            o1.y = (a.y + b.y + c.y + s5) * 0.25f;
            a = h2f2(z0.w); b = h2f2(z1.w); c = h2f2(z2.w);
            o1.z = (a.x + b.x + c.x + s6) * 0.25f;
            o1.w = (a.y + b.y + c.y + s7) * 0.25f;
            float4* ap = (float4*)(acc + ro);
            ap[0] = o0;
            ap[1] = o1;
        }
    }
}

extern "C" void kernel_launch(void* const* d_in, const int* in_sizes, int n_in,
                              void* d_out, int out_size, void* d_ws, size_t ws_size,
                              hipStream_t stream) {
    const float* user_emb  = (const float*)d_in[0];
    const float* item_emb  = (const float*)d_in[1];
    const float* edge_norm = (const float*)d_in[2];
    const int*   edge_src  = (const int*)d_in[3];
    const int*   edge_dst  = (const int*)d_in[4];
    float* acc = (float*)d_out;

    char* w = (char*)d_ws;
    ushort* egoA  = (ushort*)w;                      w += (size_t)NODE_FLOATS * 2;   // 19.2 MB
    ushort* egoB  = (ushort*)w;                      w += (size_t)NODE_FLOATS * 2;   // 19.2 MB
    u64*   pairs  = (u64*)w;                         w += (size_t)N_EDGES * 8;       // 16 MB
    int*   rowPtr = (int*)w;                         w += (size_t)(N_NODES + 4) * 4;
    int*   bucketCount  = (int*)w;                   w += (size_t)NCNT * 4;
    int*   bucketOffset = (int*)w;                   w += (size_t)(NCNT + 4) * 4;
    int*   gCur   = (int*)w;                         w += (size_t)NCNT * 4;
    // bpair (16 MB, dead after csr_finalize) and egoC (19.2 MB, born at
    // layer-2 gather) share the tail region: lifetimes don't overlap.
    u64*   bpair  = (u64*)w;
    ushort* egoC  = (ushort*)w;

    const int T = 256;
    const int EW_BLOCKS = 2048;
    const int GATHER_BLOCKS = (N_NODES + 7) / 8;     // 18750

    lgcn_init<<<EW_BLOCKS, T, 0, stream>>>(
        (const float4*)user_emb, (const float4*)item_emb, (uint2*)egoA);

    zero_ints<<<NCNT / T, T, 0, stream>>>(bucketCount, NCNT);
    bucket_hist<<<NTILE, BT, 0, stream>>>(edge_src, bucketCount);
    bucket_scan<<<1, 1024, 0, stream>>>(bucketCount, bucketOffset, gCur, rowPtr);
    bucket_scatter<<<NTILE, BT, 0, stream>>>(edge_src, edge_dst, edge_norm,
                                             gCur, bpair);
    csr_finalize<<<NBUCKET, 1024, 0, stream>>>(bucketOffset, bpair,
                                               rowPtr, pairs);

    // Layer 1: ego0(A) -> ego1(B)             (nego only)
    lgcn_gather<<<GATHER_BLOCKS, T, 0, stream>>>(egoA, egoB, acc,
                                                 (const ushort*)0, (const ushort*)0,
                                                 rowPtr, pairs, 0);
    // Layer 2: ego1(B) -> ego2(C)             (nego only)
    lgcn_gather<<<GATHER_BLOCKS, T, 0, stream>>>(egoB, egoC, acc,
                                                 (const ushort*)0, (const ushort*)0,
                                                 rowPtr, pairs, 0);
    // Layer 3: ego2(C) -> s; acc = (A + B + C + s) / 4
    lgcn_gather<<<GATHER_BLOCKS, T, 0, stream>>>(egoC, (ushort*)0, acc,
                                                 egoA, egoB,
                                                 rowPtr, pairs, 1);
}

// Round 10
// 329.006 us; speedup vs baseline: 1.5180x; 1.0068x over previous
//
#include <hip/hip_runtime.h>
#include <hip/hip_fp16.h>

// LightGCN 3-layer propagation, pull-based CSR, fp16 ego intermediates.
// Round 16: gather declared at structural floor (245MB FETCH invariant
// across dst-sort experiment; 3.85 TB/s random-row ceiling). Prep pass,
// structure-preserving:
//  (1) bucket_hist FUSED into lgcn_init (block-role split; hist's
//      latency-bound atomics hide under init's 57.6MB stream).
//  (2) bucketCount zeroed via hipMemsetAsync (launch deleted).
//  (3) csr_finalize reverted to the simple verified 512-bin sort
//      (round-15's wide key was a null on gather FETCH).
//  Gather/scatter/scan byte-identical to verified round-13 code.

#define NUM_USERS 100000
#define NUM_ITEMS 50000
#define EMB_DIM   64
#define N_EDGES   2000000
#define N_NODES   (NUM_USERS + NUM_ITEMS)          // 150000
#define NODE_FLOATS (N_NODES * EMB_DIM)            // 9,600,000
#define NODE_F4     (NODE_FLOATS / 4)              // 2,400,000

#define NBUCKET  512
#define NPB      293        // nodes per bucket; 512*293 = 150016 >= 150000
#define NPART    8          // reservation partitions (XCD heuristic)
#define NCNT     (NBUCKET * NPART)                  // 4096
#define BT       512        // threads in bucket passes
#define VPT      8          // edges per thread in bucket passes
#define TILE     (BT * VPT)                         // 4096
#define NTILE    ((N_EDGES + TILE - 1) / TILE)      // 489
#define INITB    1024       // init-role blocks in the fused kernel

typedef unsigned int uint;
typedef unsigned short ushort;
typedef unsigned long long u64;

__device__ __forceinline__ float2 h2f2(uint u) {
    __half2 h = *reinterpret_cast<const __half2*>(&u);
    return __half22float2(h);
}
__device__ __forceinline__ uint f2h2(float a, float b) {
    __half2 h = __floats2half2_rn(a, b);
    return *reinterpret_cast<uint*>(&h);
}

// ---------- fused: egoA(fp16) = concat(user,item)  +  bucket histogram ----
// Blocks [0, NTILE) run the histogram role; blocks [NTILE, NTILE+INITB)
// run the init role. Independent work, one launch: hist's LDS-atomic
// latency hides under init's streaming.
__global__ __launch_bounds__(BT) void init_and_hist(
        const float4* __restrict__ user,
        const float4* __restrict__ item,
        uint2* __restrict__ egoA,
        const int* __restrict__ src,
        int* __restrict__ bucketCount) {
    int t = threadIdx.x;
    if (blockIdx.x < NTILE) {
        __shared__ int cnt[NBUCKET];
        int part = blockIdx.x & (NPART - 1);
        cnt[t] = 0;
        __syncthreads();
        int base = blockIdx.x * TILE + t;
        #pragma unroll
        for (int k = 0; k < VPT; ++k) {
            int e = base + k * BT;
            if (e < N_EDGES) atomicAdd(&cnt[src[e] / NPB], 1);
        }
        __syncthreads();
        int c = cnt[t];
        if (c) atomicAdd(&bucketCount[t * NPART + part], c);
    } else {
        const int n_user4 = NUM_USERS * EMB_DIM / 4;
        int bid = blockIdx.x - NTILE;
        for (int i = bid * BT + t; i < NODE_F4; i += INITB * BT) {
            float4 v = (i < n_user4) ? user[i] : item[i - n_user4];
            egoA[i] = make_uint2(f2h2(v.x, v.y), f2h2(v.z, v.w));
        }
    }
}

// ---------- scan over 4096 (bucket,part) counters (1 block, 1024 thr) ----------
__global__ __launch_bounds__(1024) void bucket_scan(const int* __restrict__ bucketCount,
                                                    int* __restrict__ bucketOffset,
                                                    int* __restrict__ gCur,
                                                    int* __restrict__ rowPtr) {
    __shared__ int s[1024];
    int t = threadIdx.x;
    int4 c = *(const int4*)(bucketCount + t * 4);
    int sum = c.x + c.y + c.z + c.w;
    s[t] = sum;
    __syncthreads();
    for (int off = 1; off < 1024; off <<= 1) {
        int x = (t >= off) ? s[t - off] : 0;
        __syncthreads();
        s[t] += x;
        __syncthreads();
    }
    int base = s[t] - sum;   // exclusive
    int i0 = t * 4;
    bucketOffset[i0]     = base;
    bucketOffset[i0 + 1] = base + c.x;
    bucketOffset[i0 + 2] = base + c.x + c.y;
    bucketOffset[i0 + 3] = base + c.x + c.y + c.z;
    gCur[i0]     = base;
    gCur[i0 + 1] = base + c.x;
    gCur[i0 + 2] = base + c.x + c.y;
    gCur[i0 + 3] = base + c.x + c.y + c.z;
    if (t == 0) {
        bucketOffset[NCNT] = N_EDGES;
        rowPtr[N_NODES] = N_EDGES;
    }
}

// ---------- pass B: scatter packed edges into (bucket,part) runs ----------
// packed u64: [norm:32][src_local:9][dst:18]
__global__ __launch_bounds__(BT) void bucket_scatter(const int* __restrict__ src,
                                                     const int* __restrict__ dst,
                                                     const float* __restrict__ norm,
                                                     int* __restrict__ gCur,
                                                     u64* __restrict__ bpair) {
    __shared__ int cnt[NBUCKET];
    __shared__ int bbase[NBUCKET];
    int t = threadIdx.x;
    int part = blockIdx.x & (NPART - 1);
    cnt[t] = 0;
    __syncthreads();
    int base = blockIdx.x * TILE + t;
    #pragma unroll
    for (int k = 0; k < VPT; ++k) {
        int e = base + k * BT;
        if (e < N_EDGES) atomicAdd(&cnt[src[e] / NPB], 1);
    }
    __syncthreads();
    int c = cnt[t];
    bbase[t] = c ? atomicAdd(&gCur[t * NPART + part], c) : 0;
    __syncthreads();
    cnt[t] = 0;
    __syncthreads();
    #pragma unroll
    for (int k = 0; k < VPT; ++k) {
        int e = base + k * BT;
        if (e < N_EDGES) {
            int s = src[e];
            int b = s / NPB;
            int sl = s - b * NPB;                    // 0..292
            int r = atomicAdd(&cnt[b], 1);
            uint lo = (uint)dst[e] | ((uint)sl << 18);
            u64 packed = (u64)lo | ((u64)(uint)__float_as_uint(norm[e]) << 32);
            bpair[bbase[b] + r] = packed;
        }
    }
}

// ---------- pass C: per-bucket CSR finalize (counting sort by src_local) ----------
__global__ __launch_bounds__(1024) void csr_finalize(const int* __restrict__ bucketOffset,
                                                     const u64* __restrict__ bpair,
                                                     int* __restrict__ rowPtr,
                                                     u64* __restrict__ pairs) {
    __shared__ int cnt[NBUCKET];
    __shared__ int cur[NBUCKET];
    int b = blockIdx.x;
    int t = threadIdx.x;          // 1024 threads
    int beg = bucketOffset[b * NPART];
    int end = bucketOffset[b * NPART + NPART];
    int nodeBase = b * NPB;

    if (t < NBUCKET) cnt[t] = 0;
    __syncthreads();
    for (int i = beg + t; i < end; i += 1024) {
        uint lo = (uint)bpair[i];
        atomicAdd(&cnt[(lo >> 18) & 0x1FF], 1);
    }
    __syncthreads();
    int v = (t < NBUCKET) ? cnt[t] : 0;
    for (int off = 1; off < NBUCKET; off <<= 1) {     // inclusive scan, 512-wide
        int x = (t >= off && t < NBUCKET) ? cnt[t - off] : 0;
        __syncthreads();
        if (t < NBUCKET) cnt[t] += x;
        __syncthreads();
    }
    if (t < NBUCKET) {
        int excl = cnt[t] - v;
        cur[t] = excl;
        int node = nodeBase + t;
        if (t < NPB && node < N_NODES) rowPtr[node] = beg + excl;
    }
    __syncthreads();
    for (int i = beg + t; i < end; i += 1024) {
        u64 p = bpair[i];
        int s = ((uint)p >> 18) & 0x1FF;
        int r = atomicAdd(&cur[s], 1);
        pairs[beg + r] = p;
    }
}

// ---------- gather: 2 nodes/wave, 4 streams x 2-deep unroll per node ----------
// (verified round-13 kernel, unchanged)
// finalMode==0: nego = fp16(s)                    (no acc access)
// finalMode==1: acc  = (e0 + e1 + ego + s) * 0.25 (no nego write)
__global__ void lgcn_gather(const ushort* __restrict__ ego,
                            ushort* __restrict__ nego,
                            float* __restrict__ acc,
                            const ushort* __restrict__ e0,
                            const ushort* __restrict__ e1,
                            const int* __restrict__ rowPtr,
                            const u64* __restrict__ pairs,
                            int finalMode) {
    // 256 threads = 4 waves = 8 nodes (one node per 32-lane half-wave)
    int node   = blockIdx.x * 8 + (threadIdx.x >> 5);
    int lane32 = threadIdx.x & 31;
    int g      = lane32 >> 3;       // 4 edge streams per node
    int sub    = lane32 & 7;        // uint4 position within the 128B row
    if (node >= N_NODES) return;
    int beg = rowPtr[node];
    int end = rowPtr[node + 1];

    float a0 = 0.f, a1 = 0.f, a2 = 0.f, a3 = 0.f;
    float a4 = 0.f, a5 = 0.f, a6 = 0.f, a7 = 0.f;
    float b0 = 0.f, b1 = 0.f, b2 = 0.f, b3 = 0.f;
    float b4 = 0.f, b5 = 0.f, b6 = 0.f, b7 = 0.f;

    int i = beg + g;
    for (; i + 4 < end; i += 8) {
        u64 pA = pairs[i];
        u64 pB = pairs[i + 4];
        uint loA = (uint)pA, loB = (uint)pB;
        float wA = __uint_as_float((uint)(pA >> 32));
        float wB = __uint_as_float((uint)(pB >> 32));
        uint4 rA = *(const uint4*)(ego + ((size_t)(loA & 0x3FFFF) << 6) + (sub << 3));
        uint4 rB = *(const uint4*)(ego + ((size_t)(loB & 0x3FFFF) << 6) + (sub << 3));
        float2 q;
        q = h2f2(rA.x); a0 += wA * q.x; a1 += wA * q.y;
        q = h2f2(rA.y); a2 += wA * q.x; a3 += wA * q.y;
        q = h2f2(rA.z); a4 += wA * q.x; a5 += wA * q.y;
        q = h2f2(rA.w); a6 += wA * q.x; a7 += wA * q.y;
        q = h2f2(rB.x); b0 += wB * q.x; b1 += wB * q.y;
        q = h2f2(rB.y); b2 += wB * q.x; b3 += wB * q.y;
        q = h2f2(rB.z); b4 += wB * q.x; b5 += wB * q.y;
        q = h2f2(rB.w); b6 += wB * q.x; b7 += wB * q.y;
    }
    if (i < end) {
        u64 p = pairs[i];
        uint lo = (uint)p;
        float w = __uint_as_float((uint)(p >> 32));
        uint4 r = *(const uint4*)(ego + ((size_t)(lo & 0x3FFFF) << 6) + (sub << 3));
        float2 q;
        q = h2f2(r.x); a0 += w * q.x; a1 += w * q.y;
        q = h2f2(r.y); a2 += w * q.x; a3 += w * q.y;
        q = h2f2(r.z); a4 += w * q.x; a5 += w * q.y;
        q = h2f2(r.w); a6 += w * q.x; a7 += w * q.y;
    }
    float s0 = a0 + b0, s1 = a1 + b1, s2 = a2 + b2, s3 = a3 + b3;
    float s4 = a4 + b4, s5 = a5 + b5, s6 = a6 + b6, s7 = a7 + b7;

    s0 += __shfl_down(s0, 16); s1 += __shfl_down(s1, 16);
    s2 += __shfl_down(s2, 16); s3 += __shfl_down(s3, 16);
    s4 += __shfl_down(s4, 16); s5 += __shfl_down(s5, 16);
    s6 += __shfl_down(s6, 16); s7 += __shfl_down(s7, 16);
    s0 += __shfl_down(s0, 8);  s1 += __shfl_down(s1, 8);
    s2 += __shfl_down(s2, 8);  s3 += __shfl_down(s3, 8);
    s4 += __shfl_down(s4, 8);  s5 += __shfl_down(s5, 8);
    s6 += __shfl_down(s6, 8);  s7 += __shfl_down(s7, 8);

    if (lane32 < 8) {
        size_t ro = ((size_t)node << 6) + (lane32 << 3);   // dims lane32*8..+7
        if (!finalMode) {
            uint4* np = (uint4*)(nego + ro);
            *np = make_uint4(f2h2(s0, s1), f2h2(s2, s3),
                             f2h2(s4, s5), f2h2(s6, s7));
        } else {
            uint4 z0 = *(const uint4*)(e0  + ro);
            uint4 z1 = *(const uint4*)(e1  + ro);
            uint4 z2 = *(const uint4*)(ego + ro);
            float2 a, b, c;
            float4 o0, o1;
            a = h2f2(z0.x); b = h2f2(z1.x); c = h2f2(z2.x);
            o0.x = (a.x + b.x + c.x + s0) * 0.25f;
            o0.y = (a.y + b.y + c.y + s1) * 0.25f;
            a = h2f2(z0.y); b = h2f2(z1.y); c = h2f2(z2.y);
            o0.z = (a.x + b.x + c.x + s2) * 0.25f;
            o0.w = (a.y + b.y + c.y + s3) * 0.25f;
            a = h2f2(z0.z); b = h2f2(z1.z); c = h2f2(z2.z);
            o1.x = (a.x + b.x + c.x + s4) * 0.25f;
            o1.y = (a.y + b.y + c.y + s5) * 0.25f;
            a = h2f2(z0.w); b = h2f2(z1.w); c = h2f2(z2.w);
            o1.z = (a.x + b.x + c.x + s6) * 0.25f;
            o1.w = (a.y + b.y + c.y + s7) * 0.25f;
            float4* ap = (float4*)(acc + ro);
            ap[0] = o0;
            ap[1] = o1;
        }
    }
}

extern "C" void kernel_launch(void* const* d_in, const int* in_sizes, int n_in,
                              void* d_out, int out_size, void* d_ws, size_t ws_size,
                              hipStream_t stream) {
    const float* user_emb  = (const float*)d_in[0];
    const float* item_emb  = (const float*)d_in[1];
    const float* edge_norm = (const float*)d_in[2];
    const int*   edge_src  = (const int*)d_in[3];
    const int*   edge_dst  = (const int*)d_in[4];
    float* acc = (float*)d_out;

    char* w = (char*)d_ws;
    ushort* egoA  = (ushort*)w;                      w += (size_t)NODE_FLOATS * 2;   // 19.2 MB
    ushort* egoB  = (ushort*)w;                      w += (size_t)NODE_FLOATS * 2;   // 19.2 MB
    u64*   pairs  = (u64*)w;                         w += (size_t)N_EDGES * 8;       // 16 MB
    int*   rowPtr = (int*)w;                         w += (size_t)(N_NODES + 4) * 4;
    int*   bucketCount  = (int*)w;                   w += (size_t)NCNT * 4;
    int*   bucketOffset = (int*)w;                   w += (size_t)(NCNT + 4) * 4;
    int*   gCur   = (int*)w;                         w += (size_t)NCNT * 4;
    // bpair (16 MB, dead after csr_finalize) and egoC (19.2 MB, born at
    // layer-2 gather) share the tail region: lifetimes don't overlap.
    u64*   bpair  = (u64*)w;
    ushort* egoC  = (ushort*)w;

    const int T = 256;
    const int GATHER_BLOCKS = (N_NODES + 7) / 8;     // 18750

    hipMemsetAsync(bucketCount, 0, (size_t)NCNT * 4, stream);
    init_and_hist<<<NTILE + INITB, BT, 0, stream>>>(
        (const float4*)user_emb, (const float4*)item_emb, (uint2*)egoA,
        edge_src, bucketCount);
    bucket_scan<<<1, 1024, 0, stream>>>(bucketCount, bucketOffset, gCur, rowPtr);
    bucket_scatter<<<NTILE, BT, 0, stream>>>(edge_src, edge_dst, edge_norm,
                                             gCur, bpair);
    csr_finalize<<<NBUCKET, 1024, 0, stream>>>(bucketOffset, bpair,
                                               rowPtr, pairs);

    // Layer 1: ego0(A) -> ego1(B)             (nego only)
    lgcn_gather<<<GATHER_BLOCKS, T, 0, stream>>>(egoA, egoB, acc,
                                                 (const ushort*)0, (const ushort*)0,
                                                 rowPtr, pairs, 0);
    // Layer 2: ego1(B) -> ego2(C)             (nego only)
    lgcn_gather<<<GATHER_BLOCKS, T, 0, stream>>>(egoB, egoC, acc,
                                                 (const ushort*)0, (const ushort*)0,
                                                 rowPtr, pairs, 0);
    // Layer 3: ego2(C) -> s; acc = (A + B + C + s) / 4
    lgcn_gather<<<GATHER_BLOCKS, T, 0, stream>>>(egoC, (ushort*)0, acc,
                                                 egoA, egoB,
                                                 rowPtr, pairs, 1);
}